// Round 4
// baseline (479.907 us; speedup 1.0000x reference)
//
#include <hip/hip_runtime.h>
#include <hip/hip_bf16.h>

typedef unsigned short u16;
typedef unsigned int u32;
typedef __bf16 bf16x8 __attribute__((ext_vector_type(8)));
typedef float float4v __attribute__((ext_vector_type(4)));
typedef float f32x16 __attribute__((ext_vector_type(16)));
typedef u32 u32x4 __attribute__((ext_vector_type(4)));
typedef u16 u16x4 __attribute__((ext_vector_type(4)));
typedef u16 u16x8 __attribute__((ext_vector_type(8)));

__device__ __forceinline__ u16 f2b(float f) {
  u32 u = __float_as_uint(f);
  u += 0x7fffu + ((u >> 16) & 1u);
  return (u16)(u >> 16);
}

__device__ __forceinline__ void gload16(const void* g, void* l) {
  __builtin_amdgcn_global_load_lds(
      (const __attribute__((address_space(1))) void*)g,
      (__attribute__((address_space(3))) void*)l, 16, 0, 0);
}

// ------- weight transpose+convert: fp32 (R,C) -> bf16 (C,R) ---------------
__global__ __launch_bounds__(256) void transpose_kernel(
    const float* __restrict__ in, u16* __restrict__ out, int R, int C) {
  __shared__ float t[32][33];
  int c0 = blockIdx.x * 32, r0 = blockIdx.y * 32;
  for (int i = threadIdx.y; i < 32; i += 8)
    t[i][threadIdx.x] = in[(size_t)(r0 + i) * C + c0 + threadIdx.x];
  __syncthreads();
  for (int i = threadIdx.y; i < 32; i += 8)
    out[(size_t)(c0 + i) * R + r0 + threadIdx.x] = f2b(t[threadIdx.x][i]);
}

// ------- rel-pos bias: bias2[k] = dot(rpe[k+976], w) * log2(e) ------------
__global__ __launch_bounds__(256) void bias1d_kernel(
    const float* __restrict__ table, const float* __restrict__ w,
    float* __restrict__ out) {
  int i = blockIdx.x * 256 + threadIdx.x;
  if (i >= 2047) return;
  const float* row = table + (size_t)(i + 976) * 64;
  float s = 0.f;
#pragma unroll
  for (int d = 0; d < 64; ++d) s += row[d] * w[d];
  out[i] = s * 1.4426950408889634f;
}

// ------- LayerNorm: fp32 in -> bf16 out, one wave per row of 512 ----------
__global__ __launch_bounds__(256) void ln_kernel(
    const float* __restrict__ xr, const float* __restrict__ g,
    const float* __restrict__ bta, u16* __restrict__ out) {
  int row = blockIdx.x * 4 + (threadIdx.x >> 6);
  int lane = threadIdx.x & 63;
  const float* xp = xr + (size_t)row * 512 + lane * 8;
  float4v v0 = *reinterpret_cast<const float4v*>(xp);
  float4v v1 = *reinterpret_cast<const float4v*>(xp + 4);
  float s = v0[0] + v0[1] + v0[2] + v0[3] + v1[0] + v1[1] + v1[2] + v1[3];
  float q = v0[0]*v0[0] + v0[1]*v0[1] + v0[2]*v0[2] + v0[3]*v0[3]
          + v1[0]*v1[0] + v1[1]*v1[1] + v1[2]*v1[2] + v1[3]*v1[3];
#pragma unroll
  for (int d = 1; d < 64; d <<= 1) { s += __shfl_xor(s, d); q += __shfl_xor(q, d); }
  float mu = s * (1.f / 512.f);
  float var = q * (1.f / 512.f) - mu * mu;
  float rstd = rsqrtf(var + 1e-5f);
  const float* gp = g + lane * 8;
  const float* bp = bta + lane * 8;
  u16x8 o;
#pragma unroll
  for (int e = 0; e < 4; ++e) o[e] = f2b((v0[e] - mu) * rstd * gp[e] + bp[e]);
#pragma unroll
  for (int e = 0; e < 4; ++e) o[4 + e] = f2b((v1[e] - mu) * rstd * gp[4 + e] + bp[4 + e]);
  *reinterpret_cast<u16x8*>(out + (size_t)row * 512 + lane * 8) = o;
}

// ------- MFMA GEMM BM=128,BN=128 (m97 structure) --------------------------
template<int ACT, int RES, int OUTF>
__global__ __launch_bounds__(256) void gemm_kernel(
    const u16* __restrict__ A, const u16* __restrict__ Bt,
    const float* __restrict__ bias, const float* resid,
    void* outp, int M, int N, int K) {
  __shared__ u16 Al[128 * 32];
  __shared__ u16 Bl[128 * 32];
  const int tid = threadIdx.x;
  const int lane = tid & 63;
  const int w = tid >> 6;
  const int wr = w >> 1, wc = w & 1;
  const int lg = lane >> 4, lr = lane & 15;
  const int m0 = blockIdx.y * 128, n0 = blockIdx.x * 128;
  const int gcol = (lane & 3) * 8;

  float4v acc[4][4];
#pragma unroll
  for (int i = 0; i < 4; ++i)
#pragma unroll
    for (int j = 0; j < 4; ++j) acc[i][j] = {0.f, 0.f, 0.f, 0.f};

  const u16* Abase = A + (size_t)m0 * K;
  const u16* Bbase = Bt + (size_t)n0 * K;
  const int grow = lane >> 2;

  for (int kt = 0; kt < K; kt += 32) {
    __syncthreads();
#pragma unroll
    for (int c = 0; c < 2; ++c) {
      int r = w * 32 + c * 16 + grow;
      gload16(Abase + (size_t)r * K + kt + gcol, &Al[(w * 32 + c * 16) * 32]);
      gload16(Bbase + (size_t)r * K + kt + gcol, &Bl[(w * 32 + c * 16) * 32]);
    }
    __syncthreads();
    bf16x8 af[4], bg[4];
#pragma unroll
    for (int i = 0; i < 4; ++i)
      af[i] = *reinterpret_cast<const bf16x8*>(&Al[(wr * 64 + i * 16 + lr) * 32 + lg * 8]);
#pragma unroll
    for (int j = 0; j < 4; ++j)
      bg[j] = *reinterpret_cast<const bf16x8*>(&Bl[(wc * 64 + j * 16 + lr) * 32 + lg * 8]);
#pragma unroll
    for (int i = 0; i < 4; ++i)
#pragma unroll
      for (int j = 0; j < 4; ++j)
        acc[i][j] = __builtin_amdgcn_mfma_f32_16x16x32_bf16(af[i], bg[j], acc[i][j], 0, 0, 0);
  }

#pragma unroll
  for (int i = 0; i < 4; ++i) {
    int rbase = m0 + wr * 64 + i * 16 + lg * 4;
#pragma unroll
    for (int j = 0; j < 4; ++j) {
      int c = n0 + wc * 64 + j * 16 + lr;
      float bv = bias[c];
#pragma unroll
      for (int jj = 0; jj < 4; ++jj) {
        int rr = rbase + jj;
        float v = acc[i][j][jj] + bv;
        if (ACT == 1) v = 0.5f * v * (1.0f + erff(v * 0.70710678118654752f));
        if (RES) v += resid[(size_t)rr * N + c];
        if (OUTF)
          reinterpret_cast<float*>(outp)[(size_t)rr * N + c] = v;
        else
          reinterpret_cast<u16*>(outp)[(size_t)rr * N + c] = f2b(v);
      }
    }
  }
}

// ------- MFMA GEMM BM=64,BN=128 (for N=512 shapes: 2 blocks/CU) -----------
template<int ACT, int RES, int OUTF>
__global__ __launch_bounds__(256) void gemm64_kernel(
    const u16* __restrict__ A, const u16* __restrict__ Bt,
    const float* __restrict__ bias, const float* resid,
    void* outp, int M, int N, int K) {
  __shared__ u16 Al[64 * 32];
  __shared__ u16 Bl[128 * 32];
  const int tid = threadIdx.x;
  const int lane = tid & 63;
  const int w = tid >> 6;
  const int lg = lane >> 4, lr = lane & 15;
  const int m0 = blockIdx.y * 64, n0 = blockIdx.x * 128;
  const int grow = lane >> 2;
  const int gcol = (lane & 3) * 8;

  float4v acc[4][2];
#pragma unroll
  for (int i = 0; i < 4; ++i)
#pragma unroll
    for (int j = 0; j < 2; ++j) acc[i][j] = {0.f, 0.f, 0.f, 0.f};

  const u16* Abase = A + (size_t)m0 * K;
  const u16* Bbase = Bt + (size_t)n0 * K;

  for (int kt = 0; kt < K; kt += 32) {
    __syncthreads();
    gload16(Abase + (size_t)(w * 16 + grow) * K + kt + gcol, &Al[(w * 16) * 32]);
#pragma unroll
    for (int c = 0; c < 2; ++c)
      gload16(Bbase + (size_t)(w * 32 + c * 16 + grow) * K + kt + gcol,
              &Bl[(w * 32 + c * 16) * 32]);
    __syncthreads();
    bf16x8 af[4], bg[2];
#pragma unroll
    for (int i = 0; i < 4; ++i)
      af[i] = *reinterpret_cast<const bf16x8*>(&Al[(i * 16 + lr) * 32 + lg * 8]);
#pragma unroll
    for (int j = 0; j < 2; ++j)
      bg[j] = *reinterpret_cast<const bf16x8*>(&Bl[(w * 32 + j * 16 + lr) * 32 + lg * 8]);
#pragma unroll
    for (int i = 0; i < 4; ++i)
#pragma unroll
      for (int j = 0; j < 2; ++j)
        acc[i][j] = __builtin_amdgcn_mfma_f32_16x16x32_bf16(af[i], bg[j], acc[i][j], 0, 0, 0);
  }

#pragma unroll
  for (int i = 0; i < 4; ++i) {
    int rbase = m0 + i * 16 + lg * 4;
#pragma unroll
    for (int j = 0; j < 2; ++j) {
      int c = n0 + w * 32 + j * 16 + lr;
      float bv = bias[c];
#pragma unroll
      for (int jj = 0; jj < 4; ++jj) {
        int rr = rbase + jj;
        float v = acc[i][j][jj] + bv;
        if (ACT == 1) v = 0.5f * v * (1.0f + erff(v * 0.70710678118654752f));
        if (RES) v += resid[(size_t)rr * N + c];
        if (OUTF)
          reinterpret_cast<float*>(outp)[(size_t)rr * N + c] = v;
        else
          reinterpret_cast<u16*>(outp)[(size_t)rr * N + c] = f2b(v);
      }
    }
  }
}

// ------- fused flash attention, swapped-QK^T, key-split x2 ----------------
// qkv: (B,T,3,H,64) bf16, row stride 1536. out: (B,T,512) bf16.
// grid (T/64, B*H), 256 threads / 4 waves. Waves 0-1 = q-tiles {0,1} over
// keys 0-511; waves 2-3 = same q-tiles over keys 512-1023.
// Register budget is the occupancy lever (r3 lesson: acc regs count too):
// K is staged per-group into LDS via global_load_lds with a pre-swizzled
// global source (chunk ^= row&7), freeing the 32-VGPR K prefetch and the
// 4x-redundant per-wave K L2 reads. K and V are SINGLE-buffered with a
// 2-barrier/tile schedule: [QK reads | A | stage K(t+1), V(t+1)->regs |
// softmax+pack | PV reads | B | scatter V(t+1)]. LDS = 2 groups x
// (8KB K + 8KB V) = 32 KB. __launch_bounds__(256,3) caps combined regs
// at 168 -> 3 waves/SIMD with 1024-block grid (4 blocks/CU of work).
// End: group-1 waves publish (m,l,O) via LDS overlay, group-0 merges.
template<int BIASF>
__global__ __launch_bounds__(256, 3) void attn_kernel(
    const u16* __restrict__ qkv, const float* __restrict__ bias2,
    u16* __restrict__ out) {
  __shared__ __align__(16) char smraw[32768];
  const int tid = threadIdx.x;
  const int lane = tid & 63;
  const int w = tid >> 6;          // 0..3
  const int wq = w & 1;            // q sub-tile / wave-within-group
  const int g = w >> 1;            // key-split group
  const int koff = g << 9;         // 0 or 512
  const int hl = lane >> 5;
  const int l31 = lane & 31;
  const int bh = blockIdx.y;
  const int b = bh >> 3, hh = bh & 7;
  const int q0 = blockIdx.x * 64;
  const int qr = q0 + wq * 32 + l31;
  const u16* base = qkv + (size_t)b * 1024 * 1536 + hh * 64;
  const float SC = 0.18033688011112042f;  // 0.125 * log2(e)

  char* Klds = smraw + g * 16384;
  char* Vlds = smraw + g * 16384 + 8192;

  bf16x8 qb[4];
  {
    const u16* qp = base + (size_t)qr * 1536 + hl * 8;
#pragma unroll
    for (int dc = 0; dc < 4; ++dc)
      qb[dc] = *reinterpret_cast<const bf16x8*>(qp + dc * 16);
  }

  const int gtid = tid & 127;       // within-group thread id
  const int vkey = gtid >> 1;       // 0..63  (key row this thread stages)
  const int c0 = (gtid & 1) * 32;   // dv chunk base (32 dv per thread)

  f32x16 oA = {}, oB = {};
  float mreg = -1e30f, lsum = 0.f;

  // ---- prologue: K0 -> Klds (gload, pre-swizzled src); V0 -> regs -> Vlds
#pragma unroll
  for (int i = 0; i < 4; ++i) {
    int s = (wq * 4 + i) * 64 + lane;
    int lrow = s >> 3;
    int cd = (s & 7) ^ (lrow & 7);
    gload16(base + (size_t)(koff + lrow) * 1536 + 512 + cd * 8,
            Klds + (wq * 4 + i) * 1024);
  }
  bf16x8 vr[4];
  {
    const u16* vp = base + (size_t)(koff + vkey) * 1536 + 1024 + c0;
#pragma unroll
    for (int k = 0; k < 4; ++k)
      vr[k] = *reinterpret_cast<const bf16x8*>(vp + k * 8);
  }
  {
    char* vb = Vlds;
#pragma unroll
    for (int k = 0; k < 4; ++k)
#pragma unroll
      for (int e = 0; e < 8; ++e) {
        int dv = c0 + k * 8 + e;
        *reinterpret_cast<u16*>(vb + dv * 128 +
            ((vkey * 2) ^ (((dv + (dv >> 3)) & 7) << 4))) =
            __builtin_bit_cast(u16, (__bf16)vr[k][e]);
      }
  }
  __syncthreads();   // drains K gloads (vmcnt) + makes V scatter visible

  const int kswz = l31 & 7;

  for (int t = 0; t < 8; ++t) {
    const int abskt = koff + t * 64;

    // S^T = K·Q^T, K fragments read transiently from swizzled Klds
    f32x16 sA = {}, sB = {};
#pragma unroll
    for (int dc = 0; dc < 4; ++dc) {
      bf16x8 ka = *reinterpret_cast<const bf16x8*>(
          Klds + l31 * 128 + (((dc * 2 + hl) ^ kswz) << 4));
      bf16x8 kb = *reinterpret_cast<const bf16x8*>(
          Klds + (32 + l31) * 128 + (((dc * 2 + hl) ^ kswz) << 4));
      sA = __builtin_amdgcn_mfma_f32_32x32x16_bf16(ka, qb[dc], sA, 0, 0, 0);
      sB = __builtin_amdgcn_mfma_f32_32x32x16_bf16(kb, qb[dc], sB, 0, 0, 0);
    }
    __syncthreads();   // A: all QK LDS reads done; Klds reusable

    // stage next K into LDS (async) + next V into regs; both drain at B
    if (t < 7) {
      const int R0 = koff + (t + 1) * 64;
#pragma unroll
      for (int i = 0; i < 4; ++i) {
        int s = (wq * 4 + i) * 64 + lane;
        int lrow = s >> 3;
        int cd = (s & 7) ^ (lrow & 7);
        gload16(base + (size_t)(R0 + lrow) * 1536 + 512 + cd * 8,
                Klds + (wq * 4 + i) * 1024);
      }
      const u16* vp = base + (size_t)(R0 + vkey) * 1536 + 1024 + c0;
#pragma unroll
      for (int k = 0; k < 4; ++k)
        vr[k] = *reinterpret_cast<const bf16x8*>(vp + k * 8);
    }

    // scale (+bias), exp2 domain
#pragma unroll
    for (int r = 0; r < 16; ++r) {
      int key = (r & 3) + 8 * (r >> 2) + 4 * hl;
      if (BIASF) {
        sA[r] = fmaf(sA[r], SC, bias2[qr - abskt - key + 1023]);
        sB[r] = fmaf(sB[r], SC, bias2[qr - abskt - 32 - key + 1023]);
      } else {
        sA[r] *= SC;
        sB[r] *= SC;
      }
    }

    // online softmax with defer-max (THR = 8*log2e)
    float mx = fmaxf(sA[0], sB[0]);
#pragma unroll
    for (int r = 1; r < 16; ++r) mx = fmaxf(mx, fmaxf(sA[r], sB[r]));
    mx = fmaxf(mx, __shfl_xor(mx, 32));
    if (!__all(mx - mreg <= 11.5416f)) {
      float mn = fmaxf(mreg, mx);
      float al = exp2f(mreg - mn);
      mreg = mn;
      lsum *= al;
      oA *= al;
      oB *= al;
    }
    float ps = 0.f;
#pragma unroll
    for (int r = 0; r < 16; ++r) {
      float pa = exp2f(sA[r] - mreg);
      float pb = exp2f(sB[r] - mreg);
      sA[r] = pa; sB[r] = pb;
      ps += pa + pb;
    }
    lsum += ps;

    // pack P to bf16 and exchange halves -> B-frags
    u32 wa[8], wb[8], ra[8], rb[8];
#pragma unroll
    for (int i = 0; i < 8; ++i) {
      wa[i] = (__float_as_uint(sA[2 * i + 1]) & 0xFFFF0000u) |
              (__float_as_uint(sA[2 * i]) >> 16);
      wb[i] = (__float_as_uint(sB[2 * i + 1]) & 0xFFFF0000u) |
              (__float_as_uint(sB[2 * i]) >> 16);
    }
#pragma unroll
    for (int i = 0; i < 8; ++i) {
      ra[i] = (u32)__shfl_xor((int)wa[i], 32);
      rb[i] = (u32)__shfl_xor((int)wb[i], 32);
    }
    u32x4 f00 = {hl ? ra[2] : wa[0], hl ? ra[3] : wa[1],
                 hl ? wa[2] : ra[0], hl ? wa[3] : ra[1]};
    u32x4 f01 = {hl ? ra[6] : wa[4], hl ? ra[7] : wa[5],
                 hl ? wa[6] : ra[4], hl ? wa[7] : ra[5]};
    u32x4 f10 = {hl ? rb[2] : wb[0], hl ? rb[3] : wb[1],
                 hl ? wb[2] : rb[0], hl ? wb[3] : rb[1]};
    u32x4 f11 = {hl ? rb[6] : wb[4], hl ? rb[7] : wb[5],
                 hl ? wb[6] : rb[4], hl ? wb[7] : rb[5]};
    bf16x8 p00 = __builtin_bit_cast(bf16x8, f00);
    bf16x8 p01 = __builtin_bit_cast(bf16x8, f01);
    bf16x8 p10 = __builtin_bit_cast(bf16x8, f10);
    bf16x8 p11 = __builtin_bit_cast(bf16x8, f11);

    // O^T += V^T · P from Vlds (single buffer)
    const char* vbc = Vlds;
    const int sl0 = ((l31 + (l31 >> 3)) & 7) << 4;
    const int sl1 = (((32 + l31) + ((32 + l31) >> 3)) & 7) << 4;
    const char* vp0 = vbc + l31 * 128;
    const char* vp1 = vbc + (32 + l31) * 128;
    const int cb = hl * 16;
    bf16x8 va;
    va = *reinterpret_cast<const bf16x8*>(vp0 + ((cb + 0) ^ sl0));
    oA = __builtin_amdgcn_mfma_f32_32x32x16_bf16(va, p00, oA, 0, 0, 0);
    va = *reinterpret_cast<const bf16x8*>(vp0 + ((cb + 32) ^ sl0));
    oA = __builtin_amdgcn_mfma_f32_32x32x16_bf16(va, p01, oA, 0, 0, 0);
    va = *reinterpret_cast<const bf16x8*>(vp0 + ((cb + 64) ^ sl0));
    oA = __builtin_amdgcn_mfma_f32_32x32x16_bf16(va, p10, oA, 0, 0, 0);
    va = *reinterpret_cast<const bf16x8*>(vp0 + ((cb + 96) ^ sl0));
    oA = __builtin_amdgcn_mfma_f32_32x32x16_bf16(va, p11, oA, 0, 0, 0);
    va = *reinterpret_cast<const bf16x8*>(vp1 + ((cb + 0) ^ sl1));
    oB = __builtin_amdgcn_mfma_f32_32x32x16_bf16(va, p00, oB, 0, 0, 0);
    va = *reinterpret_cast<const bf16x8*>(vp1 + ((cb + 32) ^ sl1));
    oB = __builtin_amdgcn_mfma_f32_32x32x16_bf16(va, p01, oB, 0, 0, 0);
    va = *reinterpret_cast<const bf16x8*>(vp1 + ((cb + 64) ^ sl1));
    oB = __builtin_amdgcn_mfma_f32_32x32x16_bf16(va, p10, oB, 0, 0, 0);
    va = *reinterpret_cast<const bf16x8*>(vp1 + ((cb + 96) ^ sl1));
    oB = __builtin_amdgcn_mfma_f32_32x32x16_bf16(va, p11, oB, 0, 0, 0);

    __syncthreads();   // B: PV reads done; K gloads + V reg loads drained

    // scatter next V tile into Vlds (visible to next PV via next A)
    if (t < 7) {
      char* vb = Vlds;
#pragma unroll
      for (int k = 0; k < 4; ++k)
#pragma unroll
        for (int e = 0; e < 8; ++e) {
          int dv = c0 + k * 8 + e;
          *reinterpret_cast<u16*>(vb + dv * 128 +
              ((vkey * 2) ^ (((dv + (dv >> 3)) & 7) << 4))) =
              __builtin_bit_cast(u16, (__bf16)vr[k][e]);
        }
    }
  }

  // ---- key-split combine: group 1 publishes, group 0 merges + stores ----
  float* cmb = reinterpret_cast<float*>(smraw);            // overlays K/V
  float* ml  = reinterpret_cast<float*>(smraw + 24576);
  if (g) {
    float* cw = cmb + (size_t)(wq * 64 + lane) * 36;       // padded stride
#pragma unroll
    for (int i = 0; i < 16; ++i) cw[i] = oA[i];
#pragma unroll
    for (int i = 0; i < 16; ++i) cw[16 + i] = oB[i];
    ml[(wq * 64 + lane) * 2 + 0] = mreg;
    ml[(wq * 64 + lane) * 2 + 1] = lsum;
  }
  __syncthreads();
  if (!g) {
    const float* cr = cmb + (size_t)(wq * 64 + lane) * 36;
    float m1 = ml[(wq * 64 + lane) * 2 + 0];
    float l1 = ml[(wq * 64 + lane) * 2 + 1];
    float m01 = fmaxf(mreg, m1);
    float a0 = exp2f(mreg - m01);
    float a1 = exp2f(m1 - m01);
    float ls = lsum * a0 + l1 * a1;
    ls += __shfl_xor(ls, 32);
    float inv = 1.f / ls;
#pragma unroll
    for (int i = 0; i < 16; ++i) oA[i] = oA[i] * a0 + cr[i] * a1;
#pragma unroll
    for (int i = 0; i < 16; ++i) oB[i] = oB[i] * a0 + cr[16 + i] * a1;

    size_t orow = (size_t)(b * 1024 + qr) * 512 + hh * 64;
#pragma unroll
    for (int gg = 0; gg < 4; ++gg) {
      u16x4 pk;
#pragma unroll
      for (int e = 0; e < 4; ++e) pk[e] = f2b(oA[gg * 4 + e] * inv);
      *reinterpret_cast<u16x4*>(out + orow + gg * 8 + hl * 4) = pk;
#pragma unroll
      for (int e = 0; e < 4; ++e) pk[e] = f2b(oB[gg * 4 + e] * inv);
      *reinterpret_cast<u16x4*>(out + orow + 32 + gg * 8 + hl * 4) = pk;
    }
  }
}

extern "C" void kernel_launch(void* const* d_in, const int* in_sizes, int n_in,
                              void* d_out, int out_size, void* d_ws, size_t ws_size,
                              hipStream_t stream) {
  (void)in_sizes; (void)n_in; (void)out_size; (void)ws_size;
  const float* x        = (const float*)d_in[0];
  const float* ns_g     = (const float*)d_in[2];
  const float* ns_b     = (const float*)d_in[3];
  const float* nt_g     = (const float*)d_in[4];
  const float* nt_b     = (const float*)d_in[5];
  const float* nf_g     = (const float*)d_in[6];
  const float* nf_b     = (const float*)d_in[7];
  const float* s_qkv_w  = (const float*)d_in[8];
  const float* s_qkv_b  = (const float*)d_in[9];
  const float* s_proj_w = (const float*)d_in[10];
  const float* s_proj_b = (const float*)d_in[11];
  const float* t_qkv_w  = (const float*)d_in[12];
  const float* t_qkv_b  = (const float*)d_in[13];
  const float* t_proj_w = (const float*)d_in[14];
  const float* t_proj_b = (const float*)d_in[15];
  const float* rpe_tab  = (const float*)d_in[16];
  const float* rpe_w    = (const float*)d_in[17];
  const float* ff_w1    = (const float*)d_in[18];
  const float* ff_b1    = (const float*)d_in[19];
  const float* ff_w2    = (const float*)d_in[20];
  const float* ff_b2    = (const float*)d_in[21];

  char* ws = (char*)d_ws;
  float* xr    = (float*)(ws);                 // 16.78 MB fp32 residual
  u16*   lnb   = (u16*)(ws + 16777216);        // 8.39 MB bf16 LN output
  u16*   big   = (u16*)(ws + 25165824);        // qkv bf16 / ffn hidden
  float* bias2 = (float*)(ws + 50331648);      // 8 KB (past qkv end; dead before ffn)
  u16*   wT    = (u16*)(ws + 58720256);        // 8.39 MB transposed bf16 weights
  u16* sqkvT  = wT;
  u16* tqkvT  = wT + 786432;
  u16* sprojT = wT + 1572864;
  u16* tprojT = wT + 1835008;
  u16* ff1T   = wT + 2097152;
  u16* ff2T   = wT + 3145728;
  u16* ao     = (u16*)d_out;     // attention output scratch
  float* outp = (float*)d_out;

  dim3 tb(32, 8);
  transpose_kernel<<<dim3(48, 16), tb, 0, stream>>>(s_qkv_w, sqkvT, 512, 1536);
  transpose_kernel<<<dim3(48, 16), tb, 0, stream>>>(t_qkv_w, tqkvT, 512, 1536);
  transpose_kernel<<<dim3(16, 16), tb, 0, stream>>>(s_proj_w, sprojT, 512, 512);
  transpose_kernel<<<dim3(16, 16), tb, 0, stream>>>(t_proj_w, tprojT, 512, 512);
  transpose_kernel<<<dim3(64, 16), tb, 0, stream>>>(ff_w1, ff1T, 512, 2048);
  transpose_kernel<<<dim3(16, 64), tb, 0, stream>>>(ff_w2, ff2T, 2048, 512);
  bias1d_kernel<<<8, 256, 0, stream>>>(rpe_tab, rpe_w, bias2);

  // --- spatial attention block ---
  ln_kernel<<<2048, 256, 0, stream>>>(x, ns_g, ns_b, lnb);
  gemm_kernel<0, 0, 0><<<dim3(12, 64), 256, 0, stream>>>(
      lnb, sqkvT, s_qkv_b, nullptr, big, 8192, 1536, 512);
  attn_kernel<0><<<dim3(16, 64), 256, 0, stream>>>(big, nullptr, ao);
  gemm64_kernel<0, 1, 1><<<dim3(4, 128), 256, 0, stream>>>(
      ao, sprojT, s_proj_b, x, xr, 8192, 512, 512);
  // --- temporal attention block ---
  ln_kernel<<<2048, 256, 0, stream>>>(xr, nt_g, nt_b, lnb);
  gemm_kernel<0, 0, 0><<<dim3(12, 64), 256, 0, stream>>>(
      lnb, tqkvT, t_qkv_b, nullptr, big, 8192, 1536, 512);
  attn_kernel<1><<<dim3(16, 64), 256, 0, stream>>>(big, bias2, ao);
  gemm64_kernel<0, 1, 1><<<dim3(4, 128), 256, 0, stream>>>(
      ao, tprojT, t_proj_b, xr, xr, 8192, 512, 512);
  // --- FFN block ---
  ln_kernel<<<2048, 256, 0, stream>>>(xr, nf_g, nf_b, lnb);
  gemm_kernel<1, 0, 0><<<dim3(16, 64), 256, 0, stream>>>(
      lnb, ff1T, ff_b1, nullptr, big, 8192, 2048, 512);
  gemm64_kernel<0, 1, 1><<<dim3(4, 128), 256, 0, stream>>>(
      big, ff2T, ff_b2, xr, outp, 8192, 512, 2048);
}

// Round 5
// 331.210 us; speedup vs baseline: 1.4490x; 1.4490x over previous
//
#include <hip/hip_runtime.h>
#include <hip/hip_bf16.h>

typedef unsigned short u16;
typedef unsigned int u32;
typedef __bf16 bf16x8 __attribute__((ext_vector_type(8)));
typedef float float4v __attribute__((ext_vector_type(4)));
typedef float f32x16 __attribute__((ext_vector_type(16)));
typedef u32 u32x4 __attribute__((ext_vector_type(4)));
typedef u16 u16x4 __attribute__((ext_vector_type(4)));
typedef u16 u16x8 __attribute__((ext_vector_type(8)));

__device__ __forceinline__ u16 f2b(float f) {
  u32 u = __float_as_uint(f);
  u += 0x7fffu + ((u >> 16) & 1u);
  return (u16)(u >> 16);
}

__device__ __forceinline__ void gload16(const void* g, void* l) {
  __builtin_amdgcn_global_load_lds(
      (const __attribute__((address_space(1))) void*)g,
      (__attribute__((address_space(3))) void*)l, 16, 0, 0);
}

// ------- weight transpose+convert: fp32 (R,C) -> bf16 (C,R) ---------------
__global__ __launch_bounds__(256) void transpose_kernel(
    const float* __restrict__ in, u16* __restrict__ out, int R, int C) {
  __shared__ float t[32][33];
  int c0 = blockIdx.x * 32, r0 = blockIdx.y * 32;
  for (int i = threadIdx.y; i < 32; i += 8)
    t[i][threadIdx.x] = in[(size_t)(r0 + i) * C + c0 + threadIdx.x];
  __syncthreads();
  for (int i = threadIdx.y; i < 32; i += 8)
    out[(size_t)(c0 + i) * R + r0 + threadIdx.x] = f2b(t[threadIdx.x][i]);
}

// ------- rel-pos bias: bias2[k] = dot(rpe[k+976], w) * log2(e) ------------
__global__ __launch_bounds__(256) void bias1d_kernel(
    const float* __restrict__ table, const float* __restrict__ w,
    float* __restrict__ out) {
  int i = blockIdx.x * 256 + threadIdx.x;
  if (i >= 2047) return;
  const float* row = table + (size_t)(i + 976) * 64;
  float s = 0.f;
#pragma unroll
  for (int d = 0; d < 64; ++d) s += row[d] * w[d];
  out[i] = s * 1.4426950408889634f;
}

// ------- LayerNorm: fp32 in -> bf16 out, one wave per row of 512 ----------
__global__ __launch_bounds__(256) void ln_kernel(
    const float* __restrict__ xr, const float* __restrict__ g,
    const float* __restrict__ bta, u16* __restrict__ out) {
  int row = blockIdx.x * 4 + (threadIdx.x >> 6);
  int lane = threadIdx.x & 63;
  const float* xp = xr + (size_t)row * 512 + lane * 8;
  float4v v0 = *reinterpret_cast<const float4v*>(xp);
  float4v v1 = *reinterpret_cast<const float4v*>(xp + 4);
  float s = v0[0] + v0[1] + v0[2] + v0[3] + v1[0] + v1[1] + v1[2] + v1[3];
  float q = v0[0]*v0[0] + v0[1]*v0[1] + v0[2]*v0[2] + v0[3]*v0[3]
          + v1[0]*v1[0] + v1[1]*v1[1] + v1[2]*v1[2] + v1[3]*v1[3];
#pragma unroll
  for (int d = 1; d < 64; d <<= 1) { s += __shfl_xor(s, d); q += __shfl_xor(q, d); }
  float mu = s * (1.f / 512.f);
  float var = q * (1.f / 512.f) - mu * mu;
  float rstd = rsqrtf(var + 1e-5f);
  const float* gp = g + lane * 8;
  const float* bp = bta + lane * 8;
  u16x8 o;
#pragma unroll
  for (int e = 0; e < 4; ++e) o[e] = f2b((v0[e] - mu) * rstd * gp[e] + bp[e]);
#pragma unroll
  for (int e = 0; e < 4; ++e) o[4 + e] = f2b((v1[e] - mu) * rstd * gp[4 + e] + bp[4 + e]);
  *reinterpret_cast<u16x8*>(out + (size_t)row * 512 + lane * 8) = o;
}

// ------- MFMA GEMM BM=128,BN=128 (m97 structure) --------------------------
template<int ACT, int RES, int OUTF>
__global__ __launch_bounds__(256) void gemm_kernel(
    const u16* __restrict__ A, const u16* __restrict__ Bt,
    const float* __restrict__ bias, const float* resid,
    void* outp, int M, int N, int K) {
  __shared__ u16 Al[128 * 32];
  __shared__ u16 Bl[128 * 32];
  const int tid = threadIdx.x;
  const int lane = tid & 63;
  const int w = tid >> 6;
  const int wr = w >> 1, wc = w & 1;
  const int lg = lane >> 4, lr = lane & 15;
  const int m0 = blockIdx.y * 128, n0 = blockIdx.x * 128;
  const int gcol = (lane & 3) * 8;

  float4v acc[4][4];
#pragma unroll
  for (int i = 0; i < 4; ++i)
#pragma unroll
    for (int j = 0; j < 4; ++j) acc[i][j] = {0.f, 0.f, 0.f, 0.f};

  const u16* Abase = A + (size_t)m0 * K;
  const u16* Bbase = Bt + (size_t)n0 * K;
  const int grow = lane >> 2;

  for (int kt = 0; kt < K; kt += 32) {
    __syncthreads();
#pragma unroll
    for (int c = 0; c < 2; ++c) {
      int r = w * 32 + c * 16 + grow;
      gload16(Abase + (size_t)r * K + kt + gcol, &Al[(w * 32 + c * 16) * 32]);
      gload16(Bbase + (size_t)r * K + kt + gcol, &Bl[(w * 32 + c * 16) * 32]);
    }
    __syncthreads();
    bf16x8 af[4], bg[4];
#pragma unroll
    for (int i = 0; i < 4; ++i)
      af[i] = *reinterpret_cast<const bf16x8*>(&Al[(wr * 64 + i * 16 + lr) * 32 + lg * 8]);
#pragma unroll
    for (int j = 0; j < 4; ++j)
      bg[j] = *reinterpret_cast<const bf16x8*>(&Bl[(wc * 64 + j * 16 + lr) * 32 + lg * 8]);
#pragma unroll
    for (int i = 0; i < 4; ++i)
#pragma unroll
      for (int j = 0; j < 4; ++j)
        acc[i][j] = __builtin_amdgcn_mfma_f32_16x16x32_bf16(af[i], bg[j], acc[i][j], 0, 0, 0);
  }

#pragma unroll
  for (int i = 0; i < 4; ++i) {
    int rbase = m0 + wr * 64 + i * 16 + lg * 4;
#pragma unroll
    for (int j = 0; j < 4; ++j) {
      int c = n0 + wc * 64 + j * 16 + lr;
      float bv = bias[c];
#pragma unroll
      for (int jj = 0; jj < 4; ++jj) {
        int rr = rbase + jj;
        float v = acc[i][j][jj] + bv;
        if (ACT == 1) v = 0.5f * v * (1.0f + erff(v * 0.70710678118654752f));
        if (RES) v += resid[(size_t)rr * N + c];
        if (OUTF)
          reinterpret_cast<float*>(outp)[(size_t)rr * N + c] = v;
        else
          reinterpret_cast<u16*>(outp)[(size_t)rr * N + c] = f2b(v);
      }
    }
  }
}

// ------- MFMA GEMM BM=64,BN=128 (for N=512 shapes: 2 blocks/CU) -----------
template<int ACT, int RES, int OUTF>
__global__ __launch_bounds__(256) void gemm64_kernel(
    const u16* __restrict__ A, const u16* __restrict__ Bt,
    const float* __restrict__ bias, const float* resid,
    void* outp, int M, int N, int K) {
  __shared__ u16 Al[64 * 32];
  __shared__ u16 Bl[128 * 32];
  const int tid = threadIdx.x;
  const int lane = tid & 63;
  const int w = tid >> 6;
  const int lg = lane >> 4, lr = lane & 15;
  const int m0 = blockIdx.y * 64, n0 = blockIdx.x * 128;
  const int grow = lane >> 2;
  const int gcol = (lane & 3) * 8;

  float4v acc[4][2];
#pragma unroll
  for (int i = 0; i < 4; ++i)
#pragma unroll
    for (int j = 0; j < 2; ++j) acc[i][j] = {0.f, 0.f, 0.f, 0.f};

  const u16* Abase = A + (size_t)m0 * K;
  const u16* Bbase = Bt + (size_t)n0 * K;

  for (int kt = 0; kt < K; kt += 32) {
    __syncthreads();
    gload16(Abase + (size_t)(w * 16 + grow) * K + kt + gcol, &Al[(w * 16) * 32]);
#pragma unroll
    for (int c = 0; c < 2; ++c)
      gload16(Bbase + (size_t)(w * 32 + c * 16 + grow) * K + kt + gcol,
              &Bl[(w * 32 + c * 16) * 32]);
    __syncthreads();
    bf16x8 af[4], bg[2];
#pragma unroll
    for (int i = 0; i < 4; ++i)
      af[i] = *reinterpret_cast<const bf16x8*>(&Al[(i * 16 + lr) * 32 + lg * 8]);
#pragma unroll
    for (int j = 0; j < 2; ++j)
      bg[j] = *reinterpret_cast<const bf16x8*>(&Bl[(w * 32 + j * 16 + lr) * 32 + lg * 8]);
#pragma unroll
    for (int i = 0; i < 4; ++i)
#pragma unroll
      for (int j = 0; j < 2; ++j)
        acc[i][j] = __builtin_amdgcn_mfma_f32_16x16x32_bf16(af[i], bg[j], acc[i][j], 0, 0, 0);
  }

#pragma unroll
  for (int i = 0; i < 4; ++i) {
    int rbase = m0 + i * 16 + lg * 4;
#pragma unroll
    for (int j = 0; j < 2; ++j) {
      int c = n0 + w * 32 + j * 16 + lr;
      float bv = bias[c];
#pragma unroll
      for (int jj = 0; jj < 4; ++jj) {
        int rr = rbase + jj;
        float v = acc[i][j][jj] + bv;
        if (ACT == 1) v = 0.5f * v * (1.0f + erff(v * 0.70710678118654752f));
        if (RES) v += resid[(size_t)rr * N + c];
        if (OUTF)
          reinterpret_cast<float*>(outp)[(size_t)rr * N + c] = v;
        else
          reinterpret_cast<u16*>(outp)[(size_t)rr * N + c] = f2b(v);
      }
    }
  }
}

// ------- fused flash attention, swapped-QK^T, pipelined -------------------
// qkv: (B,T,3,H,64) bf16, row stride 1536. out: (B,T,512) bf16.
// Round-0 structure (measured 79.7 us): grid (T/128, B*H), 4 waves, wave
// owns 32 q-rows. K direct from global (L2-resident), V double-buffered in
// LDS with conflict-free slot swizzle. Occupancy is register-quantum-capped
// at 2 waves/SIMD (r2/r3/r4 ledger: total regs ~190; quantum steps at
// 64/128/256 -> any (128,256] allocation = 2 waves/SIMD; forcing <=128
// spills catastrophically). So this round cuts per-wave critical path:
//  - V-scatter re-partitioned to 4 keys x 4 dv per thread, written as
//    4x ds_write_b64 (in-register 4x4 transpose) instead of 16x
//    ds_write_b16 -- identical final LDS layout (swizzle is 16B-granular).
//  - s_setprio(1) around both MFMA clusters (T5, attn-verified +4-7%).
template<int BIASF>
__global__ __launch_bounds__(256) void attn_kernel(
    const u16* __restrict__ qkv, const float* __restrict__ bias2,
    u16* __restrict__ out) {
  __shared__ u16 Vt[2][64 * 64];  // [buf][dv][key], slot-swizzled
  const int tid = threadIdx.x;
  const int lane = tid & 63;
  const int w = tid >> 6;
  const int hl = lane >> 5;
  const int l31 = lane & 31;
  const int bh = blockIdx.y;
  const int b = bh >> 3, hh = bh & 7;
  const int q0 = blockIdx.x * 128;
  const int qr = q0 + w * 32 + l31;
  const u16* base = qkv + (size_t)b * 1024 * 1536 + hh * 64;
  const float SC = 0.18033688011112042f;  // 0.125 * log2(e)

  bf16x8 qb[4];
  {
    const u16* qp = base + (size_t)qr * 1536 + hl * 8;
#pragma unroll
    for (int dc = 0; dc < 4; ++dc)
      qb[dc] = *reinterpret_cast<const bf16x8*>(qp + dc * 16);
  }

  const int vk4 = (tid >> 4) * 4;   // key group of 4 this thread stages
  const int dv0 = (tid & 15) * 4;   // dv chunk of 4

  f32x16 oA = {}, oB = {};
  float mreg = -1e30f, lsum = 0.f;

  // ---- prologue: V tile 0 -> Vt[0]; K tile 0 -> regs ----
  u16x4 vrow[4];
  {
    const u16* vp = base + (size_t)vk4 * 1536 + 1024 + dv0;
#pragma unroll
    for (int j = 0; j < 4; ++j)
      vrow[j] = *reinterpret_cast<const u16x4*>(vp + j * 1536);
  }
  bf16x8 ka[4], kb[4];
  {
    const u16* kp = base + (size_t)l31 * 1536 + 512 + hl * 8;
#pragma unroll
    for (int dc = 0; dc < 4; ++dc) {
      ka[dc] = *reinterpret_cast<const bf16x8*>(kp + dc * 16);
      kb[dc] = *reinterpret_cast<const bf16x8*>(kp + 32 * 1536 + dc * 16);
    }
  }
  {
    char* vb = (char*)Vt[0];
#pragma unroll
    for (int e = 0; e < 4; ++e) {
      int dv = dv0 + e;
      u16x4 wv = {vrow[0][e], vrow[1][e], vrow[2][e], vrow[3][e]};
      *reinterpret_cast<u16x4*>(vb + dv * 128 +
          ((vk4 * 2) ^ (((dv + (dv >> 3)) & 7) << 4))) = wv;
    }
  }
  __syncthreads();

  for (int t = 0; t < 16; ++t) {
    const int kt = t * 64;
    const int cur = t & 1;

    // S^T = K·Q^T from registers
    f32x16 sA = {}, sB = {};
    __builtin_amdgcn_s_setprio(1);
#pragma unroll
    for (int dc = 0; dc < 4; ++dc) {
      sA = __builtin_amdgcn_mfma_f32_32x32x16_bf16(ka[dc], qb[dc], sA, 0, 0, 0);
      sB = __builtin_amdgcn_mfma_f32_32x32x16_bf16(kb[dc], qb[dc], sB, 0, 0, 0);
    }
    __builtin_amdgcn_s_setprio(0);
    // prefetch next K and V tiles (latency hides under softmax+PV)
    if (t < 15) {
      const u16* kp = base + (size_t)(kt + 64 + l31) * 1536 + 512 + hl * 8;
#pragma unroll
      for (int dc = 0; dc < 4; ++dc) {
        ka[dc] = *reinterpret_cast<const bf16x8*>(kp + dc * 16);
        kb[dc] = *reinterpret_cast<const bf16x8*>(kp + 32 * 1536 + dc * 16);
      }
      const u16* vp = base + (size_t)(kt + 64 + vk4) * 1536 + 1024 + dv0;
#pragma unroll
      for (int j = 0; j < 4; ++j)
        vrow[j] = *reinterpret_cast<const u16x4*>(vp + j * 1536);
    }

    // scale (+bias), exp2 domain
#pragma unroll
    for (int r = 0; r < 16; ++r) {
      int key = (r & 3) + 8 * (r >> 2) + 4 * hl;
      if (BIASF) {
        sA[r] = fmaf(sA[r], SC, bias2[qr - kt - key + 1023]);
        sB[r] = fmaf(sB[r], SC, bias2[qr - kt - 32 - key + 1023]);
      } else {
        sA[r] *= SC;
        sB[r] *= SC;
      }
    }

    // online softmax with defer-max (THR = 8*log2e)
    float mx = fmaxf(sA[0], sB[0]);
#pragma unroll
    for (int r = 1; r < 16; ++r) mx = fmaxf(mx, fmaxf(sA[r], sB[r]));
    mx = fmaxf(mx, __shfl_xor(mx, 32));
    if (!__all(mx - mreg <= 11.5416f)) {
      float mn = fmaxf(mreg, mx);
      float al = exp2f(mreg - mn);
      mreg = mn;
      lsum *= al;
      oA *= al;
      oB *= al;
    }
    float ps = 0.f;
#pragma unroll
    for (int r = 0; r < 16; ++r) {
      float pa = exp2f(sA[r] - mreg);
      float pb = exp2f(sB[r] - mreg);
      sA[r] = pa; sB[r] = pb;
      ps += pa + pb;
    }
    lsum += ps;

    // pack P to bf16 and exchange halves -> B-frags
    u32 wa[8], wb[8], ra[8], rb[8];
#pragma unroll
    for (int i = 0; i < 8; ++i) {
      wa[i] = (__float_as_uint(sA[2 * i + 1]) & 0xFFFF0000u) |
              (__float_as_uint(sA[2 * i]) >> 16);
      wb[i] = (__float_as_uint(sB[2 * i + 1]) & 0xFFFF0000u) |
              (__float_as_uint(sB[2 * i]) >> 16);
    }
#pragma unroll
    for (int i = 0; i < 8; ++i) {
      ra[i] = (u32)__shfl_xor((int)wa[i], 32);
      rb[i] = (u32)__shfl_xor((int)wb[i], 32);
    }
    u32x4 f00 = {hl ? ra[2] : wa[0], hl ? ra[3] : wa[1],
                 hl ? wa[2] : ra[0], hl ? wa[3] : ra[1]};
    u32x4 f01 = {hl ? ra[6] : wa[4], hl ? ra[7] : wa[5],
                 hl ? wa[6] : ra[4], hl ? wa[7] : ra[5]};
    u32x4 f10 = {hl ? rb[2] : wb[0], hl ? rb[3] : wb[1],
                 hl ? wb[2] : rb[0], hl ? wb[3] : rb[1]};
    u32x4 f11 = {hl ? rb[6] : wb[4], hl ? rb[7] : wb[5],
                 hl ? wb[6] : rb[4], hl ? wb[7] : rb[5]};
    bf16x8 p00 = __builtin_bit_cast(bf16x8, f00);
    bf16x8 p01 = __builtin_bit_cast(bf16x8, f01);
    bf16x8 p10 = __builtin_bit_cast(bf16x8, f10);
    bf16x8 p11 = __builtin_bit_cast(bf16x8, f11);

    // O^T += V^T · P from Vt[cur]
    const char* vbc = (const char*)Vt[cur];
    const int sl0 = ((l31 + (l31 >> 3)) & 7) << 4;
    const int sl1 = (((32 + l31) + ((32 + l31) >> 3)) & 7) << 4;
    const char* vp0 = vbc + l31 * 128;
    const char* vp1 = vbc + (32 + l31) * 128;
    const int cb = hl * 16;
    bf16x8 va;
    __builtin_amdgcn_s_setprio(1);
    va = *reinterpret_cast<const bf16x8*>(vp0 + ((cb + 0) ^ sl0));
    oA = __builtin_amdgcn_mfma_f32_32x32x16_bf16(va, p00, oA, 0, 0, 0);
    va = *reinterpret_cast<const bf16x8*>(vp0 + ((cb + 32) ^ sl0));
    oA = __builtin_amdgcn_mfma_f32_32x32x16_bf16(va, p01, oA, 0, 0, 0);
    va = *reinterpret_cast<const bf16x8*>(vp0 + ((cb + 64) ^ sl0));
    oA = __builtin_amdgcn_mfma_f32_32x32x16_bf16(va, p10, oA, 0, 0, 0);
    va = *reinterpret_cast<const bf16x8*>(vp0 + ((cb + 96) ^ sl0));
    oA = __builtin_amdgcn_mfma_f32_32x32x16_bf16(va, p11, oA, 0, 0, 0);
    va = *reinterpret_cast<const bf16x8*>(vp1 + ((cb + 0) ^ sl1));
    oB = __builtin_amdgcn_mfma_f32_32x32x16_bf16(va, p00, oB, 0, 0, 0);
    va = *reinterpret_cast<const bf16x8*>(vp1 + ((cb + 32) ^ sl1));
    oB = __builtin_amdgcn_mfma_f32_32x32x16_bf16(va, p01, oB, 0, 0, 0);
    va = *reinterpret_cast<const bf16x8*>(vp1 + ((cb + 64) ^ sl1));
    oB = __builtin_amdgcn_mfma_f32_32x32x16_bf16(va, p10, oB, 0, 0, 0);
    va = *reinterpret_cast<const bf16x8*>(vp1 + ((cb + 96) ^ sl1));
    oB = __builtin_amdgcn_mfma_f32_32x32x16_bf16(va, p11, oB, 0, 0, 0);
    __builtin_amdgcn_s_setprio(0);

    // scatter next V tile into the other buffer (4x ds_write_b64)
    if (t < 15) {
      char* vb = (char*)Vt[cur ^ 1];
#pragma unroll
      for (int e = 0; e < 4; ++e) {
        int dv = dv0 + e;
        u16x4 wv = {vrow[0][e], vrow[1][e], vrow[2][e], vrow[3][e]};
        *reinterpret_cast<u16x4*>(vb + dv * 128 +
            ((vk4 * 2) ^ (((dv + (dv >> 3)) & 7) << 4))) = wv;
      }
    }
    __syncthreads();
  }

  lsum += __shfl_xor(lsum, 32);
  float inv = 1.f / lsum;
  size_t orow = (size_t)(b * 1024 + qr) * 512 + hh * 64;
#pragma unroll
  for (int g = 0; g < 4; ++g) {
    u16x4 pk;
#pragma unroll
    for (int e = 0; e < 4; ++e) pk[e] = f2b(oA[g * 4 + e] * inv);
    *reinterpret_cast<u16x4*>(out + orow + g * 8 + hl * 4) = pk;
#pragma unroll
    for (int e = 0; e < 4; ++e) pk[e] = f2b(oB[g * 4 + e] * inv);
    *reinterpret_cast<u16x4*>(out + orow + 32 + g * 8 + hl * 4) = pk;
  }
}

extern "C" void kernel_launch(void* const* d_in, const int* in_sizes, int n_in,
                              void* d_out, int out_size, void* d_ws, size_t ws_size,
                              hipStream_t stream) {
  (void)in_sizes; (void)n_in; (void)out_size; (void)ws_size;
  const float* x        = (const float*)d_in[0];
  const float* ns_g     = (const float*)d_in[2];
  const float* ns_b     = (const float*)d_in[3];
  const float* nt_g     = (const float*)d_in[4];
  const float* nt_b     = (const float*)d_in[5];
  const float* nf_g     = (const float*)d_in[6];
  const float* nf_b     = (const float*)d_in[7];
  const float* s_qkv_w  = (const float*)d_in[8];
  const float* s_qkv_b  = (const float*)d_in[9];
  const float* s_proj_w = (const float*)d_in[10];
  const float* s_proj_b = (const float*)d_in[11];
  const float* t_qkv_w  = (const float*)d_in[12];
  const float* t_qkv_b  = (const float*)d_in[13];
  const float* t_proj_w = (const float*)d_in[14];
  const float* t_proj_b = (const float*)d_in[15];
  const float* rpe_tab  = (const float*)d_in[16];
  const float* rpe_w    = (const float*)d_in[17];
  const float* ff_w1    = (const float*)d_in[18];
  const float* ff_b1    = (const float*)d_in[19];
  const float* ff_w2    = (const float*)d_in[20];
  const float* ff_b2    = (const float*)d_in[21];

  char* ws = (char*)d_ws;
  float* xr    = (float*)(ws);                 // 16.78 MB fp32 residual
  u16*   lnb   = (u16*)(ws + 16777216);        // 8.39 MB bf16 LN output
  u16*   big   = (u16*)(ws + 25165824);        // qkv bf16 / ffn hidden
  float* bias2 = (float*)(ws + 50331648);      // 8 KB (past qkv end; dead before ffn)
  u16*   wT    = (u16*)(ws + 58720256);        // 8.39 MB transposed bf16 weights
  u16* sqkvT  = wT;
  u16* tqkvT  = wT + 786432;
  u16* sprojT = wT + 1572864;
  u16* tprojT = wT + 1835008;
  u16* ff1T   = wT + 2097152;
  u16* ff2T   = wT + 3145728;
  u16* ao     = (u16*)d_out;     // attention output scratch
  float* outp = (float*)d_out;

  dim3 tb(32, 8);
  transpose_kernel<<<dim3(48, 16), tb, 0, stream>>>(s_qkv_w, sqkvT, 512, 1536);
  transpose_kernel<<<dim3(48, 16), tb, 0, stream>>>(t_qkv_w, tqkvT, 512, 1536);
  transpose_kernel<<<dim3(16, 16), tb, 0, stream>>>(s_proj_w, sprojT, 512, 512);
  transpose_kernel<<<dim3(16, 16), tb, 0, stream>>>(t_proj_w, tprojT, 512, 512);
  transpose_kernel<<<dim3(64, 16), tb, 0, stream>>>(ff_w1, ff1T, 512, 2048);
  transpose_kernel<<<dim3(16, 64), tb, 0, stream>>>(ff_w2, ff2T, 2048, 512);
  bias1d_kernel<<<8, 256, 0, stream>>>(rpe_tab, rpe_w, bias2);

  // --- spatial attention block ---
  ln_kernel<<<2048, 256, 0, stream>>>(x, ns_g, ns_b, lnb);
  gemm_kernel<0, 0, 0><<<dim3(12, 64), 256, 0, stream>>>(
      lnb, sqkvT, s_qkv_b, nullptr, big, 8192, 1536, 512);
  attn_kernel<0><<<dim3(8, 64), 256, 0, stream>>>(big, nullptr, ao);
  gemm64_kernel<0, 1, 1><<<dim3(4, 128), 256, 0, stream>>>(
      ao, sprojT, s_proj_b, x, xr, 8192, 512, 512);
  // --- temporal attention block ---
  ln_kernel<<<2048, 256, 0, stream>>>(xr, nt_g, nt_b, lnb);
  gemm_kernel<0, 0, 0><<<dim3(12, 64), 256, 0, stream>>>(
      lnb, tqkvT, t_qkv_b, nullptr, big, 8192, 1536, 512);
  attn_kernel<1><<<dim3(8, 64), 256, 0, stream>>>(big, bias2, ao);
  gemm64_kernel<0, 1, 1><<<dim3(4, 128), 256, 0, stream>>>(
      ao, tprojT, t_proj_b, xr, xr, 8192, 512, 512);
  // --- FFN block ---
  ln_kernel<<<2048, 256, 0, stream>>>(xr, nf_g, nf_b, lnb);
  gemm_kernel<1, 0, 0><<<dim3(16, 64), 256, 0, stream>>>(
      lnb, ff1T, ff_b1, nullptr, big, 8192, 2048, 512);
  gemm64_kernel<0, 1, 1><<<dim3(4, 128), 256, 0, stream>>>(
      big, ff2T, ff_b2, xr, outp, 8192, 512, 2048);
}